// Round 1
// baseline (886.610 us; speedup 1.0000x reference)
//
#include <hip/hip_runtime.h>
#include <math.h>

#define B_ 4
#define L_ 4096
#define D_ 256
#define A_ 64
#define M_ (B_*L_)   // 16384 flat rows

// ---------------------------------------------------------------------------
// Projection: q/k/v[m][a] = sum_d x[m][d] * W[d][a]
// grid (M_/64, 3), block 256. Each block: 64 rows x 64 cols of one matrix.
// ---------------------------------------------------------------------------
__global__ __launch_bounds__(256) void proj_kernel(
    const float* __restrict__ x,   // [M_][D_]
    const float* __restrict__ Wq,  // [D_][A_]
    const float* __restrict__ Wk,
    const float* __restrict__ Wv,
    float* __restrict__ qo,        // [M_][A_]
    float* __restrict__ ko,
    float* __restrict__ vo)
{
    constexpr int XS = D_ + 4;     // 260 floats: 16B-aligned rows, <=2-way bank aliasing
    __shared__ float xs[64 * XS];
    const int t  = threadIdx.x;
    const int m0 = blockIdx.x * 64;
    const int w  = blockIdx.y;
    const float* W  = (w == 0) ? Wq : (w == 1) ? Wk : Wv;
    float* out      = (w == 0) ? qo : (w == 1) ? ko : vo;

    // stage x tile: 64 rows x 256 cols (16 float4 per thread, coalesced)
    #pragma unroll
    for (int p = 0; p < 16; ++p) {
        int idx = p * 1024 + t * 4;       // 0..16383
        int row = idx >> 8;
        int col = idx & 255;
        float4 xv = *(const float4*)(x + (size_t)(m0 + row) * D_ + col);
        *(float4*)(&xs[row * XS + col]) = xv;
    }
    __syncthreads();

    const int a4 = (t & 15) * 4;          // 4 output cols
    const int rq = t >> 4;                // 0..15 -> 4 output rows rq*4..rq*4+3
    float acc[4][4];
    #pragma unroll
    for (int i = 0; i < 4; ++i)
        #pragma unroll
        for (int j = 0; j < 4; ++j) acc[i][j] = 0.f;

    #pragma unroll 4
    for (int d = 0; d < D_; ++d) {
        const float4 wv = *(const float4*)(W + d * A_ + a4);   // L2-resident
        #pragma unroll
        for (int i = 0; i < 4; ++i) {
            const float xv = xs[(rq * 4 + i) * XS + d];        // broadcast read
            acc[i][0] += xv * wv.x;
            acc[i][1] += xv * wv.y;
            acc[i][2] += xv * wv.z;
            acc[i][3] += xv * wv.w;
        }
    }
    #pragma unroll
    for (int i = 0; i < 4; ++i) {
        float4 o = make_float4(acc[i][0], acc[i][1], acc[i][2], acc[i][3]);
        *(float4*)(out + (size_t)(m0 + rq * 4 + i) * A_ + a4) = o;
    }
}

// ---------------------------------------------------------------------------
// Flash-style causal attention, fp32.
// grid (L_/32, B_), block 256 = 4 waves. Each wave owns 8 query rows.
// Scores phase: lane = key index within 64-key tile.
// PV phase:     lane = head dim a.
// ---------------------------------------------------------------------------
__global__ __launch_bounds__(256) void attn_kernel(
    const float* __restrict__ q,   // [B][L][A]
    const float* __restrict__ k,
    const float* __restrict__ v,
    float* __restrict__ out)       // [B][L][A]
{
    constexpr int KS = A_ + 4;            // 68: 16B-aligned rows, <=2-way bank aliasing
    __shared__ float Qs[32 * A_];         // broadcast-only reads -> no pad needed
    __shared__ float Ks[64 * KS];
    __shared__ float Vs[64 * KS];
    __shared__ float Ps[32 * A_];         // [row-in-tile][key]

    const int t    = threadIdx.x;
    const int lane = t & 63;
    const int wid  = t >> 6;
    const int b    = blockIdx.y;
    const int qt   = (gridDim.x - 1) - blockIdx.x;  // heavy q-tiles first
    const int q0   = qt * 32;
    const size_t base = (size_t)b * L_ * A_;

    // stage Q tile: 32x64 floats (2 float4 per thread, coalesced)
    #pragma unroll
    for (int p = 0; p < 2; ++p) {
        int idx = p * 1024 + t * 4;       // 0..2047
        int row = idx >> 6;
        int col = idx & 63;
        *(float4*)(&Qs[row * A_ + col]) =
            *(const float4*)(q + base + (size_t)(q0 + row) * A_ + col);
    }

    const int qrow = q0 + wid * 8;        // first query row of this wave
    float m[8], l[8], O[8];
    #pragma unroll
    for (int r = 0; r < 8; ++r) { m[r] = -INFINITY; l[r] = 0.f; O[r] = 0.f; }

    const int ntiles = (q0 + 31) / 64 + 1;
    for (int kt = 0; kt < ntiles; ++kt) {
        const int k0 = kt * 64;
        __syncthreads();   // previous PV done before Ks/Vs overwrite; Qs visible on iter 0
        {
            const int r16 = t >> 4, c4 = (t & 15) * 4;
            #pragma unroll
            for (int p = 0; p < 4; ++p) {
                int row = p * 16 + r16;
                *(float4*)(&Ks[row * KS + c4]) =
                    *(const float4*)(k + base + (size_t)(k0 + row) * A_ + c4);
                *(float4*)(&Vs[row * KS + c4]) =
                    *(const float4*)(v + base + (size_t)(k0 + row) * A_ + c4);
            }
        }
        __syncthreads();

        // ---- scores: s[r] = Q[qrow+r] . K[k0+lane] ----
        float s[8];
        #pragma unroll
        for (int r = 0; r < 8; ++r) s[r] = 0.f;
        #pragma unroll
        for (int j = 0; j < 16; ++j) {
            const float4 kv = *(const float4*)(&Ks[lane * KS + j * 4]);
            #pragma unroll
            for (int r = 0; r < 8; ++r) {
                const float4 qv = *(const float4*)(&Qs[(wid * 8 + r) * A_ + j * 4]);
                s[r] += qv.x * kv.x + qv.y * kv.y + qv.z * kv.z + qv.w * kv.w;
            }
        }

        // ---- online softmax per row ----
        #pragma unroll
        for (int r = 0; r < 8; ++r) {
            const int qg = qrow + r;
            const bool valid = (k0 + lane) <= qg;
            float sv = valid ? s[r] : -INFINITY;
            float tmax = sv;
            #pragma unroll
            for (int off = 32; off > 0; off >>= 1)
                tmax = fmaxf(tmax, __shfl_xor(tmax, off));
            const float mnew = fmaxf(m[r], tmax);
            float p = valid ? __expf(sv - mnew) : 0.f;  // select avoids masked-tile exp(0)=1 trap
            float psum = p;
            #pragma unroll
            for (int off = 32; off > 0; off >>= 1)
                psum += __shfl_xor(psum, off);
            const float alpha = __expf(m[r] - mnew);    // -inf - finite -> exp = 0 (first tile)
            m[r] = mnew;
            l[r] = l[r] * alpha + psum;
            O[r] *= alpha;
            Ps[(wid * 8 + r) * A_ + lane] = p;
        }
        __syncthreads();   // Ps ordering (conservative; also keeps waves in lockstep)

        // ---- PV: lane = a.  O[r] += sum_k P[r][k] * V[k][lane] ----
        #pragma unroll
        for (int kc = 0; kc < 16; ++kc) {
            float vv[4];
            #pragma unroll
            for (int i = 0; i < 4; ++i) vv[i] = Vs[(kc * 4 + i) * KS + lane];
            #pragma unroll
            for (int r = 0; r < 8; ++r) {
                const float4 pv = *(const float4*)(&Ps[(wid * 8 + r) * A_ + kc * 4]);
                O[r] += pv.x * vv[0] + pv.y * vv[1] + pv.z * vv[2] + pv.w * vv[3];
            }
        }
    }

    // ---- epilogue: normalize + store (coalesced, lane = a) ----
    #pragma unroll
    for (int r = 0; r < 8; ++r)
        out[base + (size_t)(qrow + r) * A_ + lane] = O[r] / l[r];
}

// ---------------------------------------------------------------------------
extern "C" void kernel_launch(void* const* d_in, const int* in_sizes, int n_in,
                              void* d_out, int out_size, void* d_ws, size_t ws_size,
                              hipStream_t stream) {
    const float* x  = (const float*)d_in[0];
    const float* Wq = (const float*)d_in[1];
    const float* Wk = (const float*)d_in[2];
    const float* Wv = (const float*)d_in[3];

    float* qb = (float*)d_ws;                   // 3 x 4 MB scratch in d_ws
    float* kb = qb + (size_t)M_ * A_;
    float* vb = kb + (size_t)M_ * A_;
    float* out = (float*)d_out;

    dim3 gp(M_ / 64, 3), bp(256);
    hipLaunchKernelGGL(proj_kernel, gp, bp, 0, stream, x, Wq, Wk, Wv, qb, kb, vb);

    dim3 ga(L_ / 32, B_), ba(256);
    hipLaunchKernelGGL(attn_kernel, ga, ba, 0, stream, qb, kb, vb, out);
}

// Round 3
// 194.049 us; speedup vs baseline: 4.5690x; 4.5690x over previous
//
#include <hip/hip_runtime.h>
#include <hip/hip_bf16.h>
#include <math.h>

#define B_ 4
#define L_ 4096
#define D_ 256
#define A_ 64
#define M_ (B_*L_)   // 16384 flat rows

typedef _Float16 half8 __attribute__((ext_vector_type(8)));
typedef __attribute__((ext_vector_type(4))) float floatx4;

__device__ __forceinline__ unsigned short f2h(float f) {
    _Float16 h = (_Float16)f;
    return __builtin_bit_cast(unsigned short, h);
}

// ---------------------------------------------------------------------------
// Projection: q/k = [M][A] fp16 row-major; v stored TRANSPOSED [B][A][L] fp16
// grid (M_/64, 3), block 256.
// ---------------------------------------------------------------------------
__global__ __launch_bounds__(256) void proj_kernel(
    const float* __restrict__ x,   // [M_][D_]
    const float* __restrict__ Wq,  // [D_][A_]
    const float* __restrict__ Wk,
    const float* __restrict__ Wv,
    unsigned short* __restrict__ qo,   // [M_][A_] fp16
    unsigned short* __restrict__ ko,   // [M_][A_] fp16
    unsigned short* __restrict__ vto)  // [B_][A_][L_] fp16 (transposed)
{
    constexpr int XS = D_ + 4;
    __shared__ float xs[64 * XS];
    const int t  = threadIdx.x;
    const int m0 = blockIdx.x * 64;
    const int w  = blockIdx.y;
    const float* W = (w == 0) ? Wq : (w == 1) ? Wk : Wv;

    #pragma unroll
    for (int p = 0; p < 16; ++p) {
        int idx = p * 1024 + t * 4;
        int row = idx >> 8;
        int col = idx & 255;
        float4 xv = *(const float4*)(x + (size_t)(m0 + row) * D_ + col);
        *(float4*)(&xs[row * XS + col]) = xv;
    }
    __syncthreads();

    const int a4 = (t & 15) * 4;
    const int rq = t >> 4;
    float acc[4][4];
    #pragma unroll
    for (int i = 0; i < 4; ++i)
        #pragma unroll
        for (int j = 0; j < 4; ++j) acc[i][j] = 0.f;

    #pragma unroll 4
    for (int d = 0; d < D_; ++d) {
        const float4 wv = *(const float4*)(W + d * A_ + a4);
        #pragma unroll
        for (int i = 0; i < 4; ++i) {
            const float xv = xs[(rq * 4 + i) * XS + d];
            acc[i][0] += xv * wv.x;
            acc[i][1] += xv * wv.y;
            acc[i][2] += xv * wv.z;
            acc[i][3] += xv * wv.w;
        }
    }

    if (w < 2) {
        unsigned short* o = (w == 0) ? qo : ko;
        #pragma unroll
        for (int i = 0; i < 4; ++i) {
            ushort4 s;
            s.x = f2h(acc[i][0]); s.y = f2h(acc[i][1]);
            s.z = f2h(acc[i][2]); s.w = f2h(acc[i][3]);
            *(ushort4*)(o + (size_t)(m0 + rq * 4 + i) * A_ + a4) = s;
        }
    } else {
        const int bb = m0 >> 12;          // blocks never straddle batch (L_=4096)
        const int l0 = m0 & (L_ - 1);
        #pragma unroll
        for (int j = 0; j < 4; ++j) {
            ushort4 s;
            s.x = f2h(acc[0][j]); s.y = f2h(acc[1][j]);
            s.z = f2h(acc[2][j]); s.w = f2h(acc[3][j]);
            *(ushort4*)(vto + ((size_t)(bb * A_ + a4 + j)) * L_ + l0 + rq * 4) = s;
        }
    }
}

// ---------------------------------------------------------------------------
// MFMA flash attention (fp16 inputs, fp32 accumulate).
// grid (L_/32, B_), block 256 = 4 waves: (qsub 0/1) x (key-phase 0/1).
// Each wave: 16 queries, every other 64-key tile; flash-split merge via LDS.
// mfma_f32_16x16x32_f16. Layouts (m89-verified, dtype-independent):
//   A: A[m=lane&15][k=(lane>>4)*8+j]   B: B[k=(lane>>4)*8+j][n=lane&15]
//   C: col=lane&15, row=(lane>>4)*4+reg
// LDS K/V rows padded to 72 elems (144B): b128 reads are 2-way aliased = free.
// ---------------------------------------------------------------------------
__global__ __launch_bounds__(256) void attn_kernel(
    const unsigned short* __restrict__ qb,  // [B][L][A] fp16
    const unsigned short* __restrict__ kb,  // [B][L][A] fp16
    const unsigned short* __restrict__ vt,  // [B][A][L] fp16
    float* __restrict__ out)                // [B][L][A] f32
{
    __shared__ __align__(16) unsigned short smem[23040];  // 46 KB
    unsigned short* Ks = smem;            // 2 tiles x 64x72
    unsigned short* Vs = smem + 9216;     // 2 tiles x 64x72
    unsigned short* Ps = smem + 18432;    // 4 waves x 16x72

    const int t    = threadIdx.x;
    const int lane = t & 63;
    const int wid  = t >> 6;
    const int qsub = wid >> 1;
    const int ph   = wid & 1;
    const int c    = lane & 15;
    const int g    = lane >> 4;
    const int b    = blockIdx.y;
    const int qt   = (gridDim.x - 1) - blockIdx.x;   // heavy q-tiles first
    const int q0   = qt * 32;
    const int qrow0 = q0 + qsub * 16;

    const size_t base  = (size_t)b * L_ * A_;
    const size_t vbase = (size_t)b * A_ * L_;

    // Q fragments for 2 k-steps (d = 32*s + g*8 .. +7), direct from global
    half8 qf[2];
    {
        const unsigned short* qp = qb + base + (size_t)(qrow0 + c) * A_ + g * 8;
        qf[0] = *(const half8*)(qp);
        qf[1] = *(const half8*)(qp + 32);
    }

    floatx4 O4[4];
    float mrow[4], lrow[4];
    #pragma unroll
    for (int nt = 0; nt < 4; ++nt) O4[nt] = (floatx4){0.f, 0.f, 0.f, 0.f};
    #pragma unroll
    for (int r = 0; r < 4; ++r) { mrow[r] = -INFINITY; lrow[r] = 0.f; }

    const int Tmax  = ((q0 + 31) >> 6) + 1;      // k-tiles needed by heaviest row
    const int nIt   = (Tmax + 1) >> 1;
    const int ktmax = (qrow0 + 15) >> 6;         // last tile this wave needs
    unsigned short* Psw = Ps + wid * 1152;

    for (int it = 0; it < nIt; ++it) {
        __syncthreads();
        // ---- stage up to 2 K/V tiles (all 256 threads) ----
        #pragma unroll
        for (int tile = 0; tile < 2; ++tile) {
            const int kts = 2 * it + tile;
            if (kts < Tmax) {
                const int k0s = kts << 6;
                #pragma unroll
                for (int i = 0; i < 2; ++i) {
                    const int cid = t + (i << 8);          // 0..511
                    const int row = cid >> 3, c8 = cid & 7;
                    uint4 d = *(const uint4*)(kb + base + (size_t)k0s * 64 + cid * 8);
                    *(uint4*)(Ks + tile * 4608 + row * 72 + c8 * 8) = d;
                }
                #pragma unroll
                for (int i = 0; i < 2; ++i) {
                    const int cid = t + (i << 8);
                    const int row = cid >> 3, c8 = cid & 7;  // row = a
                    uint4 d = *(const uint4*)(vt + vbase + (size_t)row * L_ + k0s + c8 * 8);
                    *(uint4*)(Vs + tile * 4608 + row * 72 + c8 * 8) = d;
                }
            }
        }
        __syncthreads();

        const int kt = 2 * it + ph;
        if (kt > ktmax) continue;            // barriers stay convergent (loop top)
        const int k0 = kt << 6;
        const unsigned short* Kw = Ks + ph * 4608;
        const unsigned short* Vw = Vs + ph * 4608;

        // ---- QK^T ----
        floatx4 S4[4];
        #pragma unroll
        for (int nt = 0; nt < 4; ++nt) S4[nt] = (floatx4){0.f, 0.f, 0.f, 0.f};
        #pragma unroll
        for (int s = 0; s < 2; ++s) {
            #pragma unroll
            for (int nt = 0; nt < 4; ++nt) {
                half8 kf = *(const half8*)(Kw + (16 * nt + c) * 72 + 32 * s + g * 8);
                S4[nt] = __builtin_amdgcn_mfma_f32_16x16x32_f16(qf[s], kf, S4[nt], 0, 0, 0);
            }
        }

        // ---- causal mask (k0 <= qrow0 always; only diagonal tiles mask) ----
        if (k0 + 63 > qrow0) {
            #pragma unroll
            for (int nt = 0; nt < 4; ++nt)
                #pragma unroll
                for (int r = 0; r < 4; ++r)
                    if (k0 + 16 * nt + c > qrow0 + 4 * g + r) S4[nt][r] = -INFINITY;
        }

        // ---- online softmax (rows live in 16-lane groups; shfl_xor 1/2/4/8) ----
        float al[4];
        #pragma unroll
        for (int r = 0; r < 4; ++r) {
            float tm = fmaxf(fmaxf(S4[0][r], S4[1][r]), fmaxf(S4[2][r], S4[3][r]));
            tm = fmaxf(tm, __shfl_xor(tm, 1));
            tm = fmaxf(tm, __shfl_xor(tm, 2));
            tm = fmaxf(tm, __shfl_xor(tm, 4));
            tm = fmaxf(tm, __shfl_xor(tm, 8));
            const float mn = fmaxf(mrow[r], tm);
            al[r] = (mrow[r] == mn) ? 1.f : __expf(mrow[r] - mn);
            mrow[r] = mn;
            float rs = 0.f;
            #pragma unroll
            for (int nt = 0; nt < 4; ++nt) {
                float sv = S4[nt][r];
                float p  = (sv == -INFINITY) ? 0.f : __expf(sv - mn);
                S4[nt][r] = p;
                rs += p;
            }
            rs += __shfl_xor(rs, 1);
            rs += __shfl_xor(rs, 2);
            rs += __shfl_xor(rs, 4);
            rs += __shfl_xor(rs, 8);
            lrow[r] = lrow[r] * al[r] + rs;
        }

        // ---- rescale O; stash P (fp16) in wave-private LDS ----
        #pragma unroll
        for (int nt = 0; nt < 4; ++nt)
            #pragma unroll
            for (int r = 0; r < 4; ++r) {
                O4[nt][r] *= al[r];
                Psw[(4 * g + r) * 72 + 16 * nt + c] = f2h(S4[nt][r]);
            }

        // ---- PV (A-frags from Ps, B-frags from Vt) ----
        half8 pf0 = *(const half8*)(Psw + c * 72 + g * 8);
        half8 pf1 = *(const half8*)(Psw + c * 72 + 32 + g * 8);
        #pragma unroll
        for (int nt = 0; nt < 4; ++nt) {
            half8 vf0 = *(const half8*)(Vw + (16 * nt + c) * 72 + g * 8);
            O4[nt] = __builtin_amdgcn_mfma_f32_16x16x32_f16(pf0, vf0, O4[nt], 0, 0, 0);
            half8 vf1 = *(const half8*)(Vw + (16 * nt + c) * 72 + 32 + g * 8);
            O4[nt] = __builtin_amdgcn_mfma_f32_16x16x32_f16(pf1, vf1, O4[nt], 0, 0, 0);
        }
    }

    // ---- merge even/odd key-phase partials, normalize, store ----
    __syncthreads();
    float* MO = (float*)smem;            // 2 qsubs x 16 x 68 f32 (in Ks region)
    float* ML = MO + 2176;               // 2 qsubs x {m[16], l[16]}
    if (ph == 1) {
        float* MOq = MO + qsub * 1088;
        #pragma unroll
        for (int nt = 0; nt < 4; ++nt)
            #pragma unroll
            for (int r = 0; r < 4; ++r)
                MOq[(4 * g + r) * 68 + 16 * nt + c] = O4[nt][r];
        if (c < 4) {
            ML[qsub * 32 + 4 * g + c]      = mrow[c];
            ML[qsub * 32 + 16 + 4 * g + c] = lrow[c];
        }
    }
    __syncthreads();
    if (ph == 0) {
        float* MOq = MO + qsub * 1088;
        float a0[4], a1v[4], lf[4];
        #pragma unroll
        for (int r = 0; r < 4; ++r) {
            float m1 = ML[qsub * 32 + 4 * g + r];
            float l1 = ML[qsub * 32 + 16 + 4 * g + r];
            float mf = fmaxf(mrow[r], m1);
            a0[r]  = (mrow[r] == mf) ? 1.f : __expf(mrow[r] - mf);
            a1v[r] = (m1 == mf) ? 1.f : __expf(m1 - mf);   // empty phase: m1=-inf -> 0
            lf[r]  = lrow[r] * a0[r] + l1 * a1v[r];
        }
        #pragma unroll
        for (int nt = 0; nt < 4; ++nt)
            #pragma unroll
            for (int r = 0; r < 4; ++r) {
                float o = O4[nt][r] * a0[r] + MOq[(4 * g + r) * 68 + 16 * nt + c] * a1v[r];
                out[base + (size_t)(qrow0 + 4 * g + r) * A_ + 16 * nt + c] = o / lf[r];
            }
    }
}

// ---------------------------------------------------------------------------
extern "C" void kernel_launch(void* const* d_in, const int* in_sizes, int n_in,
                              void* d_out, int out_size, void* d_ws, size_t ws_size,
                              hipStream_t stream) {
    const float* x  = (const float*)d_in[0];
    const float* Wq = (const float*)d_in[1];
    const float* Wk = (const float*)d_in[2];
    const float* Wv = (const float*)d_in[3];

    unsigned short* qb = (unsigned short*)d_ws;            // 2 MB each
    unsigned short* kb = qb + (size_t)M_ * A_;
    unsigned short* vt = kb + (size_t)M_ * A_;
    float* out = (float*)d_out;

    dim3 gp(M_ / 64, 3), bp(256);
    hipLaunchKernelGGL(proj_kernel, gp, bp, 0, stream, x, Wq, Wk, Wv, qb, kb, vt);

    dim3 ga(L_ / 32, B_), ba(256);
    hipLaunchKernelGGL(attn_kernel, ga, ba, 0, stream, qb, kb, vt, out);
}

// Round 4
// 142.836 us; speedup vs baseline: 6.2072x; 1.3585x over previous
//
#include <hip/hip_runtime.h>
#include <math.h>

#define B_ 4
#define L_ 4096
#define D_ 256
#define A_ 64
#define M_ (B_*L_)   // 16384 flat rows

typedef _Float16 half4 __attribute__((ext_vector_type(4)));
typedef _Float16 half8 __attribute__((ext_vector_type(8)));
typedef __attribute__((ext_vector_type(4))) float floatx4;

__device__ __forceinline__ unsigned short f2h_(float f) {
    _Float16 h = (_Float16)f;
    return __builtin_bit_cast(unsigned short, h);
}

// ---------------------------------------------------------------------------
// wconv: W f32 [256][64] -> Wt fp16 [64][256] (transposed). Wq scaled by
// 1/ln2 so attention softmax can run in the exp2 domain (v_exp_f32 native).
// grid (3), block 256.
// ---------------------------------------------------------------------------
__global__ __launch_bounds__(256) void wconv_kernel(
    const float* __restrict__ Wq, const float* __restrict__ Wk,
    const float* __restrict__ Wv, unsigned short* __restrict__ wt)
{
    const int w = blockIdx.x, t = threadIdx.x;
    const float* W = (w == 0) ? Wq : (w == 1) ? Wk : Wv;
    unsigned short* o = wt + w * A_ * D_;
    const float scale = (w == 0) ? 1.44269504f : 1.0f;
    __shared__ float T[A_ * 260];
    #pragma unroll
    for (int p = 0; p < 16; ++p) {
        int idx = p * 256 + t;
        int d = idx >> 4, a4 = (idx & 15) * 4;
        float4 v = *(const float4*)(W + d * A_ + a4);
        T[(a4 + 0) * 260 + d] = v.x * scale;
        T[(a4 + 1) * 260 + d] = v.y * scale;
        T[(a4 + 2) * 260 + d] = v.z * scale;
        T[(a4 + 3) * 260 + d] = v.w * scale;
    }
    __syncthreads();
    const int a = t >> 2, d0 = (t & 3) * 64;
    #pragma unroll
    for (int i = 0; i < 16; ++i) {
        float4 v = *(const float4*)(&T[a * 260 + d0 + 4 * i]);
        ushort4 s;
        s.x = f2h_(v.x); s.y = f2h_(v.y); s.z = f2h_(v.z); s.w = f2h_(v.w);
        *(ushort4*)(o + a * D_ + d0 + 4 * i) = s;
    }
}

// ---------------------------------------------------------------------------
// proj (MFMA): q/k fp16 [M][64] row-major; v fp16 TRANSPOSED [B][64][L].
// grid (M/64, 3), block 256 = 4 waves (wave = 16 rows).
// A = x (fp16, staged), B = W^T from wconv. mfma_f32_16x16x32_f16.
// ---------------------------------------------------------------------------
__global__ __launch_bounds__(256) void proj_kernel(
    const float* __restrict__ x,          // [M][256] f32
    const unsigned short* __restrict__ wt,// [3][64][256] fp16 (W^T)
    unsigned short* __restrict__ qo,
    unsigned short* __restrict__ ko,
    unsigned short* __restrict__ vto)
{
    __shared__ __align__(16) unsigned short sh[2 * 64 * 264];  // Xh + Ws
    unsigned short* Xh = sh;
    unsigned short* Ws = sh + 64 * 264;
    const int t = threadIdx.x, m0 = blockIdx.x * 64, w = blockIdx.y;

    // stage x tile -> fp16 LDS [64][264]
    #pragma unroll
    for (int p = 0; p < 16; ++p) {
        int idx = p * 1024 + t * 4;
        int row = idx >> 8, col = idx & 255;
        float4 v = *(const float4*)(x + (size_t)(m0 + row) * D_ + col);
        ushort4 s;
        s.x = f2h_(v.x); s.y = f2h_(v.y); s.z = f2h_(v.z); s.w = f2h_(v.w);
        *(ushort4*)(Xh + row * 264 + col) = s;
    }
    // stage W^T [64][264]
    const unsigned short* wsrc = wt + w * A_ * D_;
    #pragma unroll
    for (int i = 0; i < 8; ++i) {
        int idx = i * 256 + t;
        int row = idx >> 5, col = (idx & 31) * 8;
        *(uint4*)(Ws + row * 264 + col) = *(const uint4*)(wsrc + row * D_ + col);
    }
    __syncthreads();

    const int lane = t & 63, wid = t >> 6, c = lane & 15, g = lane >> 4;
    half8 xa[8];
    #pragma unroll
    for (int s = 0; s < 8; ++s)
        xa[s] = *(const half8*)(Xh + (16 * wid + c) * 264 + 32 * s + 8 * g);

    #pragma unroll
    for (int nt = 0; nt < 4; ++nt) {
        floatx4 acc = {0.f, 0.f, 0.f, 0.f};
        #pragma unroll
        for (int s = 0; s < 8; ++s) {
            half8 wb = *(const half8*)(Ws + (16 * nt + c) * 264 + 32 * s + 8 * g);
            acc = __builtin_amdgcn_mfma_f32_16x16x32_f16(xa[s], wb, acc, 0, 0, 0);
        }
        // C[row=4g+r][col=c]: row -> x-row m0+16wid+4g+r, col -> a = 16nt+c
        if (w < 2) {
            unsigned short* o = (w == 0) ? qo : ko;
            #pragma unroll
            for (int r = 0; r < 4; ++r)
                o[(size_t)(m0 + 16 * wid + 4 * g + r) * A_ + 16 * nt + c] = f2h_(acc[r]);
        } else {
            const int bb = m0 >> 12, l0 = m0 & (L_ - 1);
            #pragma unroll
            for (int r = 0; r < 4; ++r)
                vto[((size_t)(bb * A_ + 16 * nt + c)) * L_ + l0 + 16 * wid + 4 * g + r] = f2h_(acc[r]);
        }
    }
}

// ---------------------------------------------------------------------------
// MFMA flash attention, S^T formulation (exp2 domain; q pre-scaled by 1/ln2).
// grid (L/32, B), block 256 = 4 waves: (qsub 0/1) x (key-phase 0/1).
// QK^T: A=K, B=Q (16x16x32) -> S^T: lane holds S^T[key=16nt+4g+r][q=c].
// Softmax: per-lane q row; reductions = shfl_xor 16/32 only.
// PV: P^T C-layout IS the K=16 B-layout -> mfma_f32_16x16x16f16, no P LDS.
// O accumulated transposed (O^T[a][q]); un-transposed via LDS in epilogue.
// V LDS cols reordered (16g+4nt+j) so A-frags are contiguous b128 reads.
// ---------------------------------------------------------------------------
__global__ __launch_bounds__(256) void attn_kernel(
    const unsigned short* __restrict__ qb,  // [B][L][64] fp16 (x 1/ln2)
    const unsigned short* __restrict__ kb,  // [B][L][64] fp16
    const unsigned short* __restrict__ vt,  // [B][64][L] fp16
    float* __restrict__ out)                // [B][L][64] f32
{
    __shared__ __align__(16) unsigned short smem[4 * 4608];  // Ks 2x4608 + Vs 2x4608 (36 KB)
    unsigned short* Ks = smem;
    unsigned short* Vs = smem + 2 * 4608;

    const int t    = threadIdx.x;
    const int lane = t & 63;
    const int wid  = t >> 6;
    const int qsub = wid >> 1;
    const int ph   = wid & 1;
    const int c    = lane & 15;
    const int g    = lane >> 4;
    const int b    = blockIdx.y;
    const int qt   = (gridDim.x - 1) - blockIdx.x;   // heavy q-tiles first
    const int q0   = qt * 32;
    const int qrow0 = q0 + qsub * 16;
    const int qme  = qrow0 + c;                      // this lane's q row

    const size_t base  = (size_t)b * L_ * A_;
    const size_t vbase = (size_t)b * A_ * L_;

    // Q fragments (B-operand layout == per-lane A layout): d = 32s + 8g + j
    half8 qf[2];
    {
        const unsigned short* qp = qb + base + (size_t)(qrow0 + c) * A_ + g * 8;
        qf[0] = *(const half8*)(qp);
        qf[1] = *(const half8*)(qp + 32);
    }

    floatx4 O4[4];          // O^T[a=16at+4g+r][q=c]
    #pragma unroll
    for (int at = 0; at < 4; ++at) O4[at] = (floatx4){0.f, 0.f, 0.f, 0.f};
    float m_ = -INFINITY, l_ = 0.f;

    const int Tmax  = ((q0 + 31) >> 6) + 1;
    const int nIt   = (Tmax + 1) >> 1;
    const int ktmax = (qrow0 + 15) >> 6;

    for (int it = 0; it < nIt; ++it) {
        __syncthreads();
        #pragma unroll
        for (int tile = 0; tile < 2; ++tile) {
            const int kts = 2 * it + tile;
            if (kts < Tmax) {
                const int k0s = kts << 6;
                // K: row-major [key][64]
                #pragma unroll
                for (int i = 0; i < 2; ++i) {
                    const int cid = t + (i << 8);
                    const int row = cid >> 3, c8 = cid & 7;
                    uint4 d = *(const uint4*)(kb + base + (size_t)k0s * 64 + cid * 8);
                    *(uint4*)(Ks + tile * 4608 + row * 72 + c8 * 8) = d;
                }
                // V^T: rows a, cols reordered: key=16nt+4g'+j stored at 16g'+4nt+j
                #pragma unroll
                for (int i = 0; i < 2; ++i) {
                    const int cid = t + (i << 8);
                    const int row = cid >> 3, c8 = cid & 7;   // row = a, keys 8c8..
                    uint4 d = *(const uint4*)(vt + vbase + (size_t)row * L_ + k0s + c8 * 8);
                    const int nt = c8 >> 1, g0 = 2 * (c8 & 1);
                    const int col0 = 16 * g0 + 4 * nt;
                    uint2 lo; lo.x = d.x; lo.y = d.y;
                    uint2 hi; hi.x = d.z; hi.y = d.w;
                    *(uint2*)(Vs + tile * 4608 + row * 72 + col0)      = lo;
                    *(uint2*)(Vs + tile * 4608 + row * 72 + col0 + 16) = hi;
                }
            }
        }
        __syncthreads();

        const int kt = 2 * it + ph;
        if (kt > ktmax) continue;        // barriers at loop top stay convergent
        const int k0 = kt << 6;
        const unsigned short* Kw = Ks + ph * 4608;
        const unsigned short* Vw = Vs + ph * 4608;

        // ---- S^T = K . Q^T  (A=K, B=Q) ----
        floatx4 S4[4];
        #pragma unroll
        for (int nt = 0; nt < 4; ++nt) S4[nt] = (floatx4){0.f, 0.f, 0.f, 0.f};
        #pragma unroll
        for (int s = 0; s < 2; ++s) {
            #pragma unroll
            for (int nt = 0; nt < 4; ++nt) {
                half8 kf = *(const half8*)(Kw + (16 * nt + c) * 72 + 32 * s + 8 * g);
                S4[nt] = __builtin_amdgcn_mfma_f32_16x16x32_f16(kf, qf[s], S4[nt], 0, 0, 0);
            }
        }

        // ---- causal mask: key = k0+16nt+4g+r > qme ----
        if (k0 + 63 > qrow0) {
            #pragma unroll
            for (int nt = 0; nt < 4; ++nt)
                #pragma unroll
                for (int r = 0; r < 4; ++r)
                    if (k0 + 16 * nt + 4 * g + r > qme) S4[nt][r] = -INFINITY;
        }

        // ---- online softmax, exp2 domain, per-lane q row ----
        float tm = fmaxf(fmaxf(fmaxf(S4[0][0], S4[0][1]), fmaxf(S4[0][2], S4[0][3])),
                         fmaxf(fmaxf(S4[1][0], S4[1][1]), fmaxf(S4[1][2], S4[1][3])));
        tm = fmaxf(tm, fmaxf(fmaxf(fmaxf(S4[2][0], S4[2][1]), fmaxf(S4[2][2], S4[2][3])),
                             fmaxf(fmaxf(S4[3][0], S4[3][1]), fmaxf(S4[3][2], S4[3][3]))));
        tm = fmaxf(tm, __shfl_xor(tm, 16));
        tm = fmaxf(tm, __shfl_xor(tm, 32));
        const float mn  = fmaxf(m_, tm);
        const float mnc = fmaxf(mn, -3.0e38f);       // guard -inf - -inf = NaN
        const float al  = exp2f(fminf(m_ - mnc, 0.f)); // m_=-inf -> 0 (l_,O are 0)
        float rs = 0.f;
        half4 pf[4];
        #pragma unroll
        for (int nt = 0; nt < 4; ++nt) {
            #pragma unroll
            for (int r = 0; r < 4; ++r) {
                float p = exp2f(S4[nt][r] - mnc);    // masked: exp2(-inf)=0
                S4[nt][r] = p;
                rs += p;
            }
            pf[nt][0] = (_Float16)S4[nt][0];
            pf[nt][1] = (_Float16)S4[nt][1];
            pf[nt][2] = (_Float16)S4[nt][2];
            pf[nt][3] = (_Float16)S4[nt][3];
        }
        rs += __shfl_xor(rs, 16);
        rs += __shfl_xor(rs, 32);
        l_ = l_ * al + rs;
        m_ = mn;
        #pragma unroll
        for (int at = 0; at < 4; ++at) O4[at] *= al;

        // ---- PV: O^T += V^T . P^T  (K=16 chained, P stays in registers) ----
        #pragma unroll
        for (int at = 0; at < 4; ++at) {
            half8 v01 = *(const half8*)(Vw + (16 * at + c) * 72 + 16 * g);
            half8 v23 = *(const half8*)(Vw + (16 * at + c) * 72 + 16 * g + 8);
            half4 va0 = __builtin_shufflevector(v01, v01, 0, 1, 2, 3);
            half4 va1 = __builtin_shufflevector(v01, v01, 4, 5, 6, 7);
            half4 va2 = __builtin_shufflevector(v23, v23, 0, 1, 2, 3);
            half4 va3 = __builtin_shufflevector(v23, v23, 4, 5, 6, 7);
            O4[at] = __builtin_amdgcn_mfma_f32_16x16x16f16(va0, pf[0], O4[at], 0, 0, 0);
            O4[at] = __builtin_amdgcn_mfma_f32_16x16x16f16(va1, pf[1], O4[at], 0, 0, 0);
            O4[at] = __builtin_amdgcn_mfma_f32_16x16x16f16(va2, pf[2], O4[at], 0, 0, 0);
            O4[at] = __builtin_amdgcn_mfma_f32_16x16x16f16(va3, pf[3], O4[at], 0, 0, 0);
        }
    }

    // ---- merge phases, un-transpose via LDS, coalesced store ----
    __syncthreads();                       // all compute done; reuse smem
    float4* Obuf = (float4*)smem;          // [4][128] float4 (8 KB)
    float2* mlb  = (float2*)(smem + 4096); // [128] (1 KB)
    float*  Ot   = (float*)(smem + 4608);  // [32][68] f32 (8.7 KB)

    if (ph == 1) {
        #pragma unroll
        for (int at = 0; at < 4; ++at) {
            float4 v; v.x = O4[at][0]; v.y = O4[at][1]; v.z = O4[at][2]; v.w = O4[at][3];
            Obuf[at * 128 + qsub * 64 + lane] = v;
        }
        float2 ml; ml.x = m_; ml.y = l_;
        mlb[qsub * 64 + lane] = ml;
    }
    __syncthreads();
    if (ph == 0) {
        const float2 ml1 = mlb[qsub * 64 + lane];
        const float mf = fmaxf(m_, ml1.x);
        const float a0 = (m_ == mf)    ? 1.f : exp2f(m_ - mf);
        const float a1 = (ml1.x == mf) ? 1.f : exp2f(ml1.x - mf);   // -inf -> 0
        const float inv = 1.f / (l_ * a0 + ml1.y * a1);
        #pragma unroll
        for (int at = 0; at < 4; ++at) {
            const float4 o1 = Obuf[at * 128 + qsub * 64 + lane];
            const float o1r[4] = {o1.x, o1.y, o1.z, o1.w};
            #pragma unroll
            for (int r = 0; r < 4; ++r)
                Ot[(qsub * 16 + c) * 68 + 16 * at + 4 * g + r] =
                    (O4[at][r] * a0 + o1r[r] * a1) * inv;
        }
    }
    __syncthreads();
    {
        const int qr = t >> 3, ccol = (t & 7) * 8;
        float4 u0 = *(const float4*)(Ot + qr * 68 + ccol);
        float4 u1 = *(const float4*)(Ot + qr * 68 + ccol + 4);
        float* op = out + base + (size_t)(q0 + qr) * A_ + ccol;
        *(float4*)(op)     = u0;
        *(float4*)(op + 4) = u1;
    }
}

// ---------------------------------------------------------------------------
extern "C" void kernel_launch(void* const* d_in, const int* in_sizes, int n_in,
                              void* d_out, int out_size, void* d_ws, size_t ws_size,
                              hipStream_t stream) {
    const float* x  = (const float*)d_in[0];
    const float* Wq = (const float*)d_in[1];
    const float* Wk = (const float*)d_in[2];
    const float* Wv = (const float*)d_in[3];

    unsigned short* qb = (unsigned short*)d_ws;            // 2 MB each
    unsigned short* kb = qb + (size_t)M_ * A_;
    unsigned short* vt = kb + (size_t)M_ * A_;
    unsigned short* wt = vt + (size_t)M_ * A_;             // 3x32 KB W^T fp16
    float* out = (float*)d_out;

    hipLaunchKernelGGL(wconv_kernel, dim3(3), dim3(256), 0, stream, Wq, Wk, Wv, wt);

    dim3 gp(M_ / 64, 3), bp(256);
    hipLaunchKernelGGL(proj_kernel, gp, bp, 0, stream, x, wt, qb, kb, vt);

    dim3 ga(L_ / 32, B_), ba(256);
    hipLaunchKernelGGL(attn_kernel, ga, ba, 0, stream, qb, kb, vt, out);
}